// Round 1
// baseline (623.385 us; speedup 1.0000x reference)
//
#include <hip/hip_runtime.h>

#define NB 2
#define NT 2048
#define ND 1024
#define NH 16
#define HD 64
#define WIN 512
#define NBH (NB*NH)      // 32
#define NCH (NT/64)      // 32 chunks of 64 along T

// ---------------------------------------------------------------- helpers
__device__ __forceinline__ void fma16(const float4 av, const float4 bv, float acc[4][4])
{
    float ar[4] = {av.x, av.y, av.z, av.w};
    float br[4] = {bv.x, bv.y, bv.z, bv.w};
#pragma unroll
    for (int r = 0; r < 4; ++r)
#pragma unroll
        for (int c = 0; c < 4; ++c)
            acc[r][c] = fmaf(ar[r], br[c], acc[r][c]);
}

__device__ __forceinline__ void store_T(float (*dst)[64], int d0, int jj,
                                        float4 a, float4 b, float4 c, float4 d)
{
    dst[d0 + 0][jj] = a.x; dst[d0 + 1][jj] = a.y; dst[d0 + 2][jj] = a.z; dst[d0 + 3][jj] = a.w;
    dst[d0 + 4][jj] = b.x; dst[d0 + 5][jj] = b.y; dst[d0 + 6][jj] = b.z; dst[d0 + 7][jj] = b.w;
    dst[d0 + 8][jj] = c.x; dst[d0 + 9][jj] = c.y; dst[d0 +10][jj] = c.z; dst[d0 +11][jj] = c.w;
    dst[d0 +12][jj] = d.x; dst[d0 +13][jj] = d.y; dst[d0 +14][jj] = d.z; dst[d0 +15][jj] = d.w;
}

// ---------------------------------------------------------------- GEMM
// C = A(MxK) @ W(KxN) + bias.  MODE 0: row-major MxN.  MODE 1: scatter to
// (B,H,T,HD) layout (BN=64 == one head per block column).
template<int MODE>
__global__ __launch_bounds__(256)
void gemm_k(const float* __restrict__ A, const float* __restrict__ W,
            const float* __restrict__ bias, float* __restrict__ C,
            int M, int N, int K)
{
    __shared__ float As[16][64];   // [k][m] (transposed store)
    __shared__ float Bs[16][64];   // [k][n]
    const int tid = threadIdx.x;
    const int tx = tid & 15, ty = tid >> 4;
    const int n0 = blockIdx.x << 6, m0 = blockIdx.y << 6;
    const int am = tid >> 2, ak = (tid & 3) << 2;   // A loader: row am, k ak..ak+3
    const int bk = tid >> 4, bn = (tid & 15) << 2;  // B loader: row bk, n bn..bn+3
    const float* Ap = A + (size_t)(m0 + am) * K + ak;
    const float* Wp = W + (size_t)bk * N + n0 + bn;

    float acc[4][4] = {};
    for (int k0 = 0; k0 < K; k0 += 16) {
        const float4 a4 = *(const float4*)(Ap + k0);
        const float4 b4 = *(const float4*)(Wp + (size_t)k0 * N);
        __syncthreads();
        As[ak + 0][am] = a4.x; As[ak + 1][am] = a4.y;
        As[ak + 2][am] = a4.z; As[ak + 3][am] = a4.w;
        *(float4*)&Bs[bk][bn] = b4;
        __syncthreads();
#pragma unroll
        for (int k = 0; k < 16; ++k) {
            const float4 av = *(const float4*)&As[k][ty << 2];
            const float4 bv = *(const float4*)&Bs[k][tx << 2];
            fma16(av, bv, acc);
        }
    }
    const float4 bias4 = *(const float4*)&bias[n0 + (tx << 2)];
    const float bb[4] = {bias4.x, bias4.y, bias4.z, bias4.w};
#pragma unroll
    for (int r = 0; r < 4; ++r) {
        const int row = m0 + (ty << 2) + r;
        float4 o;
        o.x = acc[r][0] + bb[0]; o.y = acc[r][1] + bb[1];
        o.z = acc[r][2] + bb[2]; o.w = acc[r][3] + bb[3];
        if (MODE == 0) {
            *(float4*)&C[(size_t)row * N + n0 + (tx << 2)] = o;
        } else {
            const int b = row >> 11;            // row / NT
            const int i = row & (NT - 1);
            const int h = n0 >> 6;
            *(float4*)&C[((((size_t)(b * NH + h)) << 11) + i) * HD + (tx << 2)] = o;
        }
    }
}

// ---------------------------------------------------------------- windowed-sum machinery
// Per 64-chunk prefix sums along T (lane = d).
__global__ __launch_bounds__(64)
void chunkscan_k(const float* __restrict__ g, float* __restrict__ Pin,
                 float* __restrict__ Csum)
{
    const int blk = blockIdx.x;          // bh*NCH + c
    const int lane = threadIdx.x;        // d
    const int base = (blk << 12) + lane; // (blk*64 rows) * 64 + d
    float run = 0.f;
#pragma unroll 16
    for (int t = 0; t < 64; ++t) {
        run += g[base + (t << 6)];
        Pin[base + (t << 6)] = run;
    }
    Csum[(blk << 6) + lane] = run;
}

// Scan the 32 chunk totals per (b,h) (lane = d).
__global__ __launch_bounds__(64)
void chunkpre_k(const float* __restrict__ Csum, float* __restrict__ Cpre)
{
    const int bh = blockIdx.x, lane = threadIdx.x;
    float run = 0.f;
    for (int c = 0; c < NCH; ++c) {
        run += Csum[((bh * NCH + c) << 6) + lane];
        Cpre[((bh * NCH + c) << 6) + lane] = run;
    }
}

// winsum[i] = P[i] - P[i-WIN]  (P = global prefix along T, per (b,h,d))
__global__ __launch_bounds__(256)
void winsum_k(const float* __restrict__ Pin, const float* __restrict__ Cpre,
              float* __restrict__ wout)
{
    const int idx = blockIdx.x * 256 + threadIdx.x;   // float4 index
    const int e0 = idx << 2;
    const int row = e0 >> 6;           // bh*NT + i
    const int d = e0 & 63;
    const int bh = row >> 11;
    const int i = row & (NT - 1);
    const int c = i >> 6;

    float4 p = *(const float4*)&Pin[e0];
    float ax = p.x, ay = p.y, az = p.z, aw = p.w;
    if (c > 0) {
        const float4 q = *(const float4*)&Cpre[((bh * NCH + c - 1) << 6) + d];
        ax += q.x; ay += q.y; az += q.z; aw += q.w;
    }
    if (i >= WIN) {
        const int i2 = i - WIN;
        const int c2 = i2 >> 6;
        const float4 p2 = *(const float4*)&Pin[(((bh << 11) + i2) << 6) + d];
        ax -= p2.x; ay -= p2.y; az -= p2.z; aw -= p2.w;
        if (c2 > 0) {
            const float4 q2 = *(const float4*)&Cpre[((bh * NCH + c2 - 1) << 6) + d];
            ax -= q2.x; ay -= q2.y; az -= q2.z; aw -= q2.w;
        }
    }
    *(float4*)&wout[e0] = make_float4(ax, ay, az, aw);
}

// Per row i (one wave, lane = d): denom, sum_inv (fp64), gene_fit (in-place
// over winsum), rowsum = gene_fit . winsum (fp64).
__global__ __launch_bounds__(256)
void stats_k(float* __restrict__ wing, double* __restrict__ rowsum)
{
    const int row = (blockIdx.x << 2) + (threadIdx.x >> 6);
    const int lane = threadIdx.x & 63;
    const int i = row & (NT - 1);
    const float w = wing[(row << 6) + lane];
    const double cnt = (double)((i + 1 < WIN) ? (i + 1) : WIN);
    const double denom = (double)w / cnt + 0.5;
    double s = 1.0 / denom;
#pragma unroll
    for (int off = 32; off > 0; off >>= 1) s += __shfl_xor(s, off);
    const double gf = 1.0 / (denom * s);
    double rw = gf * (double)w;
#pragma unroll
    for (int off = 32; off > 0; off >>= 1) rw += __shfl_xor(rw, off);
    wing[(row << 6) + lane] = (float)gf;
    if (lane == 0) rowsum[row] = rw;
}

// ---------------------------------------------------------------- banded attention
// Block: one (b,h) x 64-row query tile. 9 key tiles of 64.  S = GF.G^T, O += S.V.
// sT overlays gT (sync between GEMM1 and the sT store) -> 48KB static LDS.
__global__ __launch_bounds__(256)
void attn_k(const float* __restrict__ gf, const float* __restrict__ g,
            const float* __restrict__ v, const double* __restrict__ rowsum,
            float* __restrict__ outp)
{
    __shared__ float gfT[64][64];   // [d][ii]
    __shared__ float gT[64][64];    // [d][jj]  -- reused as sT[jj][ii]
    __shared__ float vsm[64][64];   // [jj][d]
    float (*sT)[64] = gT;

    const int bh = blockIdx.y, it = blockIdx.x;
    const int i0 = it << 6;
    const int tid = threadIdx.x;
    const int tx = tid & 15, ty = tid >> 4;
    const int ljj = tid >> 2, ld0 = (tid & 3) << 4;

    {   // gene_fit tile -> gfT (transposed)
        const float* src = gf + (((size_t)(bh << 11) + i0 + ljj) << 6) + ld0;
        const float4 x0 = *(const float4*)(src);
        const float4 x1 = *(const float4*)(src + 4);
        const float4 x2 = *(const float4*)(src + 8);
        const float4 x3 = *(const float4*)(src + 12);
        store_T(gfT, ld0, ljj, x0, x1, x2, x3);
    }

    float acc2[4][4] = {};
    const int t_lo = (it >= 8) ? (it - 8) : 0;
    for (int t = t_lo; t <= it; ++t) {
        const int j0 = t << 6;
        const float* gsrc = g + (((size_t)(bh << 11) + j0 + ljj) << 6) + ld0;
        const float* vsrc = v + (((size_t)(bh << 11) + j0 + ljj) << 6) + ld0;
        const float4 g0 = *(const float4*)(gsrc);
        const float4 g1 = *(const float4*)(gsrc + 4);
        const float4 g2 = *(const float4*)(gsrc + 8);
        const float4 g3 = *(const float4*)(gsrc + 12);
        const float4 v0 = *(const float4*)(vsrc);
        const float4 v1 = *(const float4*)(vsrc + 4);
        const float4 v2 = *(const float4*)(vsrc + 8);
        const float4 v3 = *(const float4*)(vsrc + 12);

        __syncthreads();             // previous GEMM2 done with gT(sT)/vsm
        store_T(gT, ld0, ljj, g0, g1, g2, g3);
        *(float4*)&vsm[ljj][ld0 + 0]  = v0;
        *(float4*)&vsm[ljj][ld0 + 4]  = v1;
        *(float4*)&vsm[ljj][ld0 + 8]  = v2;
        *(float4*)&vsm[ljj][ld0 + 12] = v3;
        __syncthreads();

        float sfr[4][4] = {};
#pragma unroll 16
        for (int k = 0; k < 64; ++k) {
            const float4 av = *(const float4*)&gfT[k][ty << 2];
            const float4 bv = *(const float4*)&gT[k][tx << 2];
            fma16(av, bv, sfr);
        }
        __syncthreads();             // everyone done reading gT before sT store

        const bool need_mask = (t == it) || (t == it - 8);
#pragma unroll
        for (int c = 0; c < 4; ++c) {
            float4 col = make_float4(sfr[0][c], sfr[1][c], sfr[2][c], sfr[3][c]);
            if (need_mask) {
                const int jg = j0 + (tx << 2) + c;
                const int ib = i0 + (ty << 2);
                if (!(jg <= ib + 0 && jg > ib + 0 - WIN)) col.x = 0.f;
                if (!(jg <= ib + 1 && jg > ib + 1 - WIN)) col.y = 0.f;
                if (!(jg <= ib + 2 && jg > ib + 2 - WIN)) col.z = 0.f;
                if (!(jg <= ib + 3 && jg > ib + 3 - WIN)) col.w = 0.f;
            }
            *(float4*)&sT[(tx << 2) + c][ty << 2] = col;
        }
        __syncthreads();

#pragma unroll 16
        for (int k = 0; k < 64; ++k) {
            const float4 av = *(const float4*)&sT[k][ty << 2];
            const float4 bv = *(const float4*)&vsm[k][tx << 2];
            fma16(av, bv, acc2);
        }
    }

    const int b = bh >> 4, h = bh & 15;
#pragma unroll
    for (int r = 0; r < 4; ++r) {
        const int i = i0 + (ty << 2) + r;
        double rs = rowsum[(bh << 11) + i];
        if (!(rs > 1e-10)) rs = 1e-10;
        const float inv = (float)(1.0 / rs);
        const float4 o = make_float4(acc2[r][0] * inv, acc2[r][1] * inv,
                                     acc2[r][2] * inv, acc2[r][3] * inv);
        *(float4*)&outp[(((size_t)(b * NT + i)) << 10) + (h << 6) + (tx << 2)] = o;
    }
}

// ---------------------------------------------------------------- launch
extern "C" void kernel_launch(void* const* d_in, const int* in_sizes, int n_in,
                              void* d_out, int out_size, void* d_ws, size_t ws_size,
                              hipStream_t stream)
{
    const float* x  = (const float*)d_in[0];
    const float* Wg = (const float*)d_in[1];
    const float* bg = (const float*)d_in[2];
    const float* Wv = (const float*)d_in[3];
    const float* bv = (const float*)d_in[4];
    const float* Wo = (const float*)d_in[5];
    const float* bo = (const float*)d_in[6];
    float* out = (float*)d_out;

    const size_t SZ = (size_t)NB * NH * NT * HD;   // 4M floats
    float* gbuf = (float*)d_ws;
    float* vbuf = gbuf + SZ;
    float* pinb = vbuf + SZ;               // chunk prefixes; later reused as attn out
    float* winb = pinb + SZ;               // winsum -> gene_fit (in place)
    float* csum = winb + SZ;               // NBH*NCH*HD = 64K floats
    float* cpre = csum + (NBH * NCH * HD);
    double* rsum = (double*)(cpre + (NBH * NCH * HD));
    float* aout = pinb;

    const int M = NB * NT;   // 4096

    gemm_k<1><<<dim3(ND >> 6, M >> 6), 256, 0, stream>>>(x, Wg, bg, gbuf, M, ND, ND);
    gemm_k<1><<<dim3(ND >> 6, M >> 6), 256, 0, stream>>>(x, Wv, bv, vbuf, M, ND, ND);
    chunkscan_k<<<NBH * NCH, 64, 0, stream>>>(gbuf, pinb, csum);
    chunkpre_k<<<NBH, 64, 0, stream>>>(csum, cpre);
    winsum_k<<<(NBH * NT * HD / 4) / 256, 256, 0, stream>>>(pinb, cpre, winb);
    stats_k<<<(NBH * NT) / 4, 256, 0, stream>>>(winb, rsum);
    attn_k<<<dim3(NT >> 6, NBH), 256, 0, stream>>>(winb, gbuf, vbuf, rsum, aout);
    gemm_k<0><<<dim3(ND >> 6, M >> 6), 256, 0, stream>>>(aout, Wo, bo, out, M, ND, ND);
}